// Round 10
// baseline (412.659 us; speedup 1.0000x reference)
//
#include <hip/hip_runtime.h>
#include <hip/hip_bf16.h>
#include <stdint.h>

#define B_DIM 8
#define L_DIM 512
#define D_DIM 1024
#define S_DIM 6144
#define M_DIM (B_DIM * S_DIM)       // 49152
#define NCHUNK 8
#define CHUNK (L_DIM / NCHUNK)      // 64
#define CSB (513 * 1024)            // floats per batch in cs ([L+1][D])

typedef __attribute__((ext_vector_type(8))) short short8;
typedef __attribute__((ext_vector_type(4))) float f32x4;
typedef __attribute__((ext_vector_type(8))) unsigned short us8;

__device__ __forceinline__ unsigned short f2bf(float f) {
    unsigned int u = __float_as_uint(f);
    u += 0x7FFFu + ((u >> 16) & 1u);
    return (unsigned short)(u >> 16);
}

// ---------------- Phase 1a: chunk_sums + wconv fused ----------------
__global__ __launch_bounds__(256) void prep_fused(const float* __restrict__ h,
                                                  float* __restrict__ csum,
                                                  const float* __restrict__ W,
                                                  unsigned short* __restrict__ Wbf) {
    if (blockIdx.x < 256) {
        int tid = blockIdx.x * 256 + threadIdx.x;   // 65536 total
        int d = tid & 1023;
        int c = (tid >> 10) & 7;
        int b = tid >> 13;
        const float* hp = h + ((size_t)b * L_DIM + c * CHUNK) * D_DIM + d;
        float s = 0.f;
        #pragma unroll 8
        for (int i = 0; i < CHUNK; ++i) s += hp[(size_t)i * D_DIM];
        csum[tid] = s;
    } else {
        int tid = (blockIdx.x - 256) * 256 + threadIdx.x;   // 131072 total
        const float4* p = (const float4*)(W + (size_t)tid * 8);
        float4 a = p[0], c = p[1];
        us8 o;
        o[0] = f2bf(a.x); o[1] = f2bf(a.y); o[2] = f2bf(a.z); o[3] = f2bf(a.w);
        o[4] = f2bf(c.x); o[5] = f2bf(c.y); o[6] = f2bf(c.z); o[7] = f2bf(c.w);
        *(us8*)&Wbf[(size_t)tid * 8] = o;
    }
}

// ---------------- Phase 1b: build cs (exclusive prefix, L+1 rows) ----------
__global__ __launch_bounds__(256) void build_cs(const float* __restrict__ h,
                                                const float* __restrict__ csum,
                                                float* __restrict__ cs) {
    int tid = blockIdx.x * 256 + threadIdx.x;   // 65536 total
    int d = tid & 1023;
    int c = (tid >> 10) & 7;
    int b = tid >> 13;
    float p = 0.f;
    for (int cc = 0; cc < c; ++cc)
        p += csum[(b << 13) + (cc << 10) + d];
    const float* hp = h + ((size_t)b * L_DIM + c * CHUNK) * D_DIM + d;
    float* cp = cs + ((size_t)b * (L_DIM + 1) + c * CHUNK) * D_DIM + d;
    if (c == 0) cp[0] = 0.f;
    #pragma unroll 8
    for (int i = 0; i < CHUNK; ++i) {
        p += hp[(size_t)i * D_DIM];
        cp[(size_t)(i + 1) * D_DIM] = p;
    }
}

// ---------------- Phase 2: span_rep -> bf16 ----------------
__global__ __launch_bounds__(256) void spanrep(const float* __restrict__ cs,
                                               const int* __restrict__ span_idx,
                                               unsigned short* __restrict__ rep) {
    int tid = blockIdx.x * 256 + threadIdx.x;   // 6,291,456 total
    int d8 = tid & 127;
    int bs = tid >> 7;                           // 0..49151
    int b = bs / S_DIM;
    int2 se = ((const int2*)span_idx)[bs];
    int st = min(max(se.x, 0), L_DIM - 1);
    int en = min(max(se.y, 0), L_DIM - 1);
    bool valid = st <= en;
    float inv = valid ? 1.0f / (float)(en - st + 1) : 0.0f;
    const float* base = cs + (size_t)b * CSB + d8 * 8;
    const float4* pe = (const float4*)(base + (size_t)(en + 1) * D_DIM);
    const float4* ps = (const float4*)(base + (size_t)st * D_DIM);
    float4 e0 = pe[0], e1 = pe[1];
    float4 s0 = ps[0], s1 = ps[1];
    us8 o;
    o[0] = f2bf((e0.x - s0.x) * inv);
    o[1] = f2bf((e0.y - s0.y) * inv);
    o[2] = f2bf((e0.z - s0.z) * inv);
    o[3] = f2bf((e0.w - s0.w) * inv);
    o[4] = f2bf((e1.x - s1.x) * inv);
    o[5] = f2bf((e1.y - s1.y) * inv);
    o[6] = f2bf((e1.z - s1.z) * inv);
    o[7] = f2bf((e1.w - s1.w) * inv);
    *(us8*)&rep[(size_t)bs * D_DIM + d8 * 8] = o;
}

// ---------------- Phase 3: GEMM 256x256xBK64, 8-phase, RACE-FIXED -----------
// 8 waves (2M x 4N), per-wave 128x64 out, acc[8][4]. LDS 128 KB: A/B x 2 bufs
// of 256x64 (row stride 128 B, XOR chunk^(r&7) — r7-proven zero-conflict,
// both-sides involution via pre-swizzled glds source).
//
// KEY FIX vs r9: vmcnt is PER-WAVE; a gate only proves MY loads landed. The
// gate must be followed by a BARRIER before any wave ds_reads the staged
// buffer. Gates now sit at END of ph3 (publishes buf1=T1, read at ph4..6) and
// END of ph7 (publishes buf0=T0+2, read at next ph0..2).
//
// Stage stream (2 glds each): prologue [B0h0,B0h1,A0h0,A0h1,B1h0,B1h1,A1h0];
// per iter: ph0 Ah1(T1) | ph1 Bh0(T0+2) | ph2 Bh1(T0+2) | ph3 Ah0(T0+2) |
//           ph4 Ah1(T0+2) | ph5 Bh0(T1+2) | ph6 Bh1(T1+2) | ph7 Ah0(T1+2).
// Gates see 14 outstanding, GATE6 leaves newest 3 STG (6 glds): ph3 drains
// through Ah1(T1); ph7 through Ah1(T0+2). Induction holds; LAST uses GATE0
// at ph3, no ph7 gate. Every restage >=1 barrier after its slot's last read.
// MFMA: ph0 c47k1(prev T1) | ph1 c03k0(T0) | ph2 c47k0(T0) | ph3 c03k1(T0) |
//       ph4 c47k1(T0) | ph5 c03k0(T1) | ph6 c47k0(T1) | ph7 c03k1(T1).
__global__ __launch_bounds__(512) void gemm_bias_relu(
    const unsigned short* __restrict__ Ag,   // rep [M][1024] bf16 bits
    const unsigned short* __restrict__ Wt,   // Wbf [N][1024] bf16 bits
    const float* __restrict__ bias,
    float* __restrict__ out) {
    constexpr int K = D_DIM, N = D_DIM;
    __shared__ __align__(16) unsigned short AsL[2 * 256 * 64];   // 64 KB
    __shared__ __align__(16) unsigned short BsL[2 * 256 * 64];   // 64 KB

    const int tid = threadIdx.x;
    const int wid = tid >> 6, lane = tid & 63;

    // 768 blocks, 96/XCD; 4 bn-siblings of one bm adjacent on one XCD.
    int blk = blockIdx.x;
    int swz = (blk & 7) * 96 + (blk >> 3);
    const int bm = swz >> 2;                  // 0..191
    const int bn = swz & 3;                   // 0..3
    const int rowM = bm * 256;
    const int colN = bn * 256;

    const int fr = lane & 15;
    const int kq = lane >> 4;                 // 0..3
    const int wr = wid >> 2, wc = wid & 3;    // 2 x 4 wave grid

    f32x4 acc[8][4];
    #pragma unroll
    for (int i = 0; i < 8; ++i)
        #pragma unroll
        for (int j = 0; j < 4; ++j) acc[i][j] = (f32x4){0.f, 0.f, 0.f, 0.f};

    short8 bq[2][2][4];   // [tile parity][ks][j]
    short8 a3[2][2][4];   // A rows 0..63 of wave's half
    short8 a7[2][2][4];   // A rows 64..127 of wave's half

#define FEN do { asm volatile("" ::: "memory"); \
                 __builtin_amdgcn_sched_barrier(0); } while (0)
#define BARR do { __builtin_amdgcn_s_barrier(); \
                  __builtin_amdgcn_sched_barrier(0); } while (0)
#define LGKM0 do { asm volatile("s_waitcnt lgkmcnt(0)" ::: "memory"); \
                   __builtin_amdgcn_sched_barrier(0); } while (0)
#define GATE6 do { asm volatile("s_waitcnt vmcnt(6)" ::: "memory"); } while (0)
#define GATE0 do { asm volatile("s_waitcnt vmcnt(0)" ::: "memory"); } while (0)

#define RD_BQ(P) do { _Pragma("unroll") for (int ks = 0; ks < 2; ++ks) \
        _Pragma("unroll") for (int j = 0; j < 4; ++j) { \
            int rb = wc * 64 + j * 16 + fr; \
            bq[P][ks][j] = *(const short8*)((const char*)BsL + (P) * 32768 \
                + rb * 128 + ((ks * 64 + kq * 16) ^ ((rb & 7) << 4))); } } while (0)

#define RD_A3(P) do { _Pragma("unroll") for (int ks = 0; ks < 2; ++ks) \
        _Pragma("unroll") for (int i = 0; i < 4; ++i) { \
            int ra = wr * 128 + i * 16 + fr; \
            a3[P][ks][i] = *(const short8*)((const char*)AsL + (P) * 32768 \
                + ra * 128 + ((ks * 64 + kq * 16) ^ ((ra & 7) << 4))); } } while (0)

#define RD_A7(P) do { _Pragma("unroll") for (int ks = 0; ks < 2; ++ks) \
        _Pragma("unroll") for (int i = 0; i < 4; ++i) { \
            int ra = wr * 128 + (i + 4) * 16 + fr; \
            a7[P][ks][i] = *(const short8*)((const char*)AsL + (P) * 32768 \
                + ra * 128 + ((ks * 64 + kq * 16) ^ ((ra & 7) << 4))); } } while (0)

#define MM3(P, KS) do { __builtin_amdgcn_s_setprio(1); \
        _Pragma("unroll") for (int i = 0; i < 4; ++i) \
        _Pragma("unroll") for (int j = 0; j < 4; ++j) \
            acc[i][j] = __builtin_amdgcn_mfma_f32_16x16x32_bf16( \
                a3[P][KS][i], bq[P][KS][j], acc[i][j], 0, 0, 0); \
        __builtin_amdgcn_s_setprio(0); } while (0)

#define MM7(P, KS) do { __builtin_amdgcn_s_setprio(1); \
        _Pragma("unroll") for (int i = 0; i < 4; ++i) \
        _Pragma("unroll") for (int j = 0; j < 4; ++j) \
            acc[4 + i][j] = __builtin_amdgcn_mfma_f32_16x16x32_bf16( \
                a7[P][KS][i], bq[P][KS][j], acc[4 + i][j], 0, 0, 0); \
        __builtin_amdgcn_s_setprio(0); } while (0)

    // stage half H (128 rows) of (ISB? B : A) of `tile` into buf BUF.
    // ci -> r=ci>>3 (0..127), c=ci&7; source chunk pre-swizzled c^(r&7);
    // LDS dest linear (wave-uniform base + lane*16).
#define STG(tile, ISB, H, BUF) do { const int kb_ = (tile) * 64; \
        _Pragma("unroll") for (int i2 = 0; i2 < 2; ++i2) { \
            int ci_ = i2 * 512 + tid; \
            int r_ = ci_ >> 3, c_ = ci_ & 7; \
            int gr_ = (H) * 128 + r_; \
            const unsigned short* s_ = ((ISB) ? Wt + (size_t)(colN + gr_) * K \
                                              : Ag + (size_t)(rowM + gr_) * K) \
                                       + kb_ + ((c_ ^ (r_ & 7)) * 8); \
            unsigned short* d_ = ((ISB) ? BsL : AsL) + (BUF) * 16384 + (size_t)(gr_ * 8 + c_) * 8; \
            __builtin_amdgcn_global_load_lds( \
                (const __attribute__((address_space(1))) void*)s_, \
                (__attribute__((address_space(3))) void*)d_, 16, 0, 0); \
        } } while (0)

#define ITER(T0, FIRST, LAST) do { \
        /* ph0 */ RD_BQ(0); STG((T0) + 1, 0, 1, 1); FEN; BARR; LGKM0; \
                  if (!(FIRST)) MM7(1, 1); FEN; BARR; \
        /* ph1 */ RD_A3(0); if (!(LAST)) STG((T0) + 2, 1, 0, 0); FEN; BARR; LGKM0; MM3(0, 0); FEN; BARR; \
        /* ph2 */ RD_A7(0); if (!(LAST)) STG((T0) + 2, 1, 1, 0); FEN; BARR; LGKM0; MM7(0, 0); FEN; BARR; \
        /* ph3 */ if (!(LAST)) { STG((T0) + 2, 0, 0, 0); FEN; GATE6; } else { GATE0; } \
                  FEN; BARR; LGKM0; MM3(0, 1); FEN; BARR; \
        /* ph4 */ RD_BQ(1); if (!(LAST)) STG((T0) + 2, 0, 1, 0); FEN; BARR; LGKM0; MM7(0, 1); FEN; BARR; \
        /* ph5 */ RD_A3(1); if (!(LAST)) STG((T0) + 3, 1, 0, 1); FEN; BARR; LGKM0; MM3(1, 0); FEN; BARR; \
        /* ph6 */ RD_A7(1); if (!(LAST)) STG((T0) + 3, 1, 1, 1); FEN; BARR; LGKM0; MM7(1, 0); FEN; BARR; \
        /* ph7 */ if (!(LAST)) { STG((T0) + 3, 0, 0, 1); FEN; GATE6; } \
                  FEN; BARR; LGKM0; MM3(1, 1); FEN; BARR; \
    } while (0)

    // prologue: FIFO mirrors steady stage stream; 7 STG = 14 glds, then
    // GATE6 (drains tile0's 4 STG) + BARRIER (publishes tile0 to all waves).
    STG(0, 1, 0, 0); STG(0, 1, 1, 0); STG(0, 0, 0, 0); STG(0, 0, 1, 0);
    STG(1, 1, 0, 1); STG(1, 1, 1, 1); STG(1, 0, 0, 1);
    FEN;
    GATE6;
    BARR;

    ITER(0, 1, 0);
    for (int T0 = 2; T0 <= 12; T0 += 2) ITER(T0, 0, 0);
    ITER(14, 0, 1);
    MM7(1, 1);                         // closing cluster c47k1(tile 15)

    // epilogue: C/D layout col=lane&15, row=(lane>>4)*4+r (m89/m91)
    const int m0 = rowM + wr * 128;
    const int n0 = colN + wc * 64;
    float bv[4];
    #pragma unroll
    for (int j = 0; j < 4; ++j) bv[j] = bias[n0 + j * 16 + fr];
    #pragma unroll
    for (int i = 0; i < 8; ++i)
        #pragma unroll
        for (int j = 0; j < 4; ++j)
            #pragma unroll
            for (int r = 0; r < 4; ++r) {
                int m = m0 + i * 16 + kq * 4 + r;
                int n = n0 + j * 16 + fr;
                float v = acc[i][j][r] + bv[j];
                out[(size_t)m * N + n] = v > 0.f ? v : 0.f;
            }
#undef FEN
#undef BARR
#undef LGKM0
#undef GATE6
#undef GATE0
#undef RD_BQ
#undef RD_A3
#undef RD_A7
#undef MM3
#undef MM7
#undef STG
#undef ITER
}

extern "C" void kernel_launch(void* const* d_in, const int* in_sizes, int n_in,
                              void* d_out, int out_size, void* d_ws, size_t ws_size,
                              hipStream_t stream) {
    const float* h = (const float*)d_in[0];
    const int* span = (const int*)d_in[1];
    const float* W = (const float*)d_in[2];
    const float* bias = (const float*)d_in[3];
    float* out = (float*)d_out;

    char* ws = (char*)d_ws;
    // ws layout (bytes):
    //   cs   : [B][L+1][D] fp32 = 16,809,984    @ 0
    //   Wbf  : [D][D]     bf16 =  2,097,152     @ 16,809,984
    //   csum : [B][8][D]  fp32 =    262,144     @ 18,907,136
    //   rep  : [M][D]     bf16 = 100,663,296    @ 19,169,280
    float* cs = (float*)(ws);
    unsigned short* Wbf = (unsigned short*)(ws + 16809984);
    float* csum = (float*)(ws + 18907136);
    unsigned short* rep = (unsigned short*)(ws + 19169280);

    prep_fused<<<768, 256, 0, stream>>>(h, csum, W, Wbf);
    build_cs<<<256, 256, 0, stream>>>(h, csum, cs);
    spanrep<<<24576, 256, 0, stream>>>(cs, span, rep);
    gemm_bias_relu<<<768, 512, 0, stream>>>(rep, Wbf, bias, out);
}